// Round 1
// baseline (1173.559 us; speedup 1.0000x reference)
//
#include <hip/hip_runtime.h>
#include <math.h>

#define B_    16
#define H_    16
#define N_    4096
#define T_    8
#define DS_   256
#define DID_  128
#define L_    8
#define K_    32
#define DHID_ 1024
#define DSTEER_ 896
#define QH_   512
#define QO_   256
#define NW_   256   // B*H walkers
#define SCORE_SCALE 0.022097086912079608f  // 1/(8*sqrt(32))

__device__ __forceinline__ float gelu_exact(float x) {
    return 0.5f * x * (1.0f + erff(x * 0.70710678118654752f));
}

// Generic tile: computes out[row][j0..j0+64) for up to 32 rows.
// in: row-major [*, DIN]. W: jmajor ? W[j*DIN+d] : W[d*JOUT+j].
// rows_s: 32 row ids in LDS (-1 = invalid). lds_tile: 32*128 floats.
__device__ void mlp_tile(const int* rows_s, const float* __restrict__ in, int DIN,
                         const float* __restrict__ W, int JOUT, int j0, bool jmajor,
                         const float* __restrict__ bias, bool act,
                         float* __restrict__ out, float* lds_tile)
{
    int tid = threadIdx.x;
    int jj  = tid & 63;
    int rg  = tid >> 6;            // wave id 0..3, 8 rows each
    int j   = j0 + jj;
    float acc[8];
#pragma unroll
    for (int r = 0; r < 8; ++r) acc[r] = 0.f;
    int nchunk = DIN >> 7;
    for (int dc = 0; dc < nchunk; ++dc) {
        __syncthreads();
#pragma unroll
        for (int it = 0; it < 4; ++it) {
            int idx4 = tid + it * 256;          // 0..1023 (32 rows * 32 float4)
            int r = idx4 >> 5, d4 = idx4 & 31;
            int row = rows_s[r];
            float4 v = make_float4(0.f, 0.f, 0.f, 0.f);
            if (row >= 0)
                v = *reinterpret_cast<const float4*>(in + (size_t)row * DIN + dc * 128 + d4 * 4);
            *reinterpret_cast<float4*>(lds_tile + r * 128 + d4 * 4) = v;
        }
        __syncthreads();
        const float4* lt4 = reinterpret_cast<const float4*>(lds_tile);
        if (jmajor) {
            const float* Wr = W + (size_t)j * DIN + dc * 128;
            for (int dd4 = 0; dd4 < 32; ++dd4) {
                float4 wv = *reinterpret_cast<const float4*>(Wr + dd4 * 4);
#pragma unroll
                for (int r = 0; r < 8; ++r) {
                    float4 sv = lt4[(rg * 8 + r) * 32 + dd4];
                    acc[r] += sv.x * wv.x + sv.y * wv.y + sv.z * wv.z + sv.w * wv.w;
                }
            }
        } else {
            const float* Wc = W + (size_t)(dc * 128) * JOUT + j;
            for (int dd4 = 0; dd4 < 32; ++dd4) {
                float w0 = Wc[(size_t)(dd4 * 4 + 0) * JOUT];
                float w1 = Wc[(size_t)(dd4 * 4 + 1) * JOUT];
                float w2 = Wc[(size_t)(dd4 * 4 + 2) * JOUT];
                float w3 = Wc[(size_t)(dd4 * 4 + 3) * JOUT];
#pragma unroll
                for (int r = 0; r < 8; ++r) {
                    float4 sv = lt4[(rg * 8 + r) * 32 + dd4];
                    acc[r] += sv.x * w0 + sv.y * w1 + sv.z * w2 + sv.w * w3;
                }
            }
        }
    }
    float bj = bias ? bias[j] : 0.f;
#pragma unroll
    for (int r = 0; r < 8; ++r) {
        int row = rows_s[rg * 8 + r];
        if (row >= 0) {
            float v = acc[r] + bj;
            if (act) v = gelu_exact(v);
            out[(size_t)row * JOUT + j] = v;
        }
    }
}

// ---------------- setup kernels ----------------

__global__ __launch_bounds__(256) void init_kernel(
    const int* __restrict__ walker_pos, const int* __restrict__ plane_idx,
    int* pos, float* mp_all, int* plane_order,
    int* chunk_plane, int* chunk_rows, int* nchunks_p)
{
    int tid = threadIdx.x;
    pos[tid] = walker_pos[tid];
    mp_all[tid] = 0.f;                       // 8*32 = 256
    __shared__ int cnt_s[8];
    __shared__ int cplane_s[16], cbase_s[16];
    __shared__ int nch_s;
    int wave = tid >> 6, lane = tid & 63;
    for (int pp = wave; pp < 8; pp += 4) {
        int base = 0;
        for (int c0 = 0; c0 < NW_; c0 += 64) {
            int w = c0 + lane;
            bool hit = (plane_idx[w] == pp);
            unsigned long long mask = __ballot(hit);
            if (hit) {
                int rank = __popcll(mask & ((1ull << lane) - 1ull));
                plane_order[pp * NW_ + base + rank] = w;
            }
            base += __popcll(mask);
        }
        if (lane == 0) cnt_s[pp] = base;
    }
    __syncthreads();
    if (tid == 0) {
        int nc = 0;
        for (int p = 0; p < 8; ++p)
            for (int s0 = 0; s0 < cnt_s[p]; s0 += 32) {
                cplane_s[nc] = p; cbase_s[nc] = s0; ++nc;
            }
        nch_s = nc;
        *nchunks_p = nc;
    }
    __syncthreads();
    int nc = nch_s;
    for (int idx = tid; idx < 16 * 32; idx += 256) {
        int c = idx >> 5, i = idx & 31;
        int v = -1;
        if (c < nc) {
            int p = cplane_s[c];
            int r = cbase_s[c] + i;
            if (r < cnt_s[p]) v = plane_order[p * NW_ + r];
        }
        chunk_rows[c * 32 + i] = v;
        if (i == 0) chunk_plane[c] = (c < nc) ? cplane_s[c] : 0;
    }
}

// keys[n] = mlp2(node_id[n]); 16 nodes per block, 256 blocks.
__global__ __launch_bounds__(256) void keys_kernel(
    const float* __restrict__ node_id, const float* __restrict__ kw1,
    const float* __restrict__ kb1, const float* __restrict__ kw2,
    const float* __restrict__ kb2, float* __restrict__ keys)
{
    __shared__ float id_s[16 * 128];
    __shared__ float kh_s[16 * 512];
    int n0 = blockIdx.x * 16;
    int tid = threadIdx.x;
#pragma unroll
    for (int it = 0; it < 2; ++it) {
        int idx4 = tid + it * 256;             // 512 float4 total
        int r = idx4 >> 5, d4 = idx4 & 31;
        *reinterpret_cast<float4*>(id_s + r * 128 + d4 * 4) =
            *reinterpret_cast<const float4*>(node_id + (size_t)(n0 + r) * 128 + d4 * 4);
    }
    __syncthreads();
    int jj = tid & 63, rg = tid >> 6;          // 4 waves, 4 rows each
    for (int jb = 0; jb < 8; ++jb) {
        int j = jb * 64 + jj;
        float acc[4] = {0.f, 0.f, 0.f, 0.f};
        const float* Wc = kw1 + j;
        for (int dd4 = 0; dd4 < 32; ++dd4) {
            float w0 = Wc[(dd4 * 4 + 0) * 512];
            float w1 = Wc[(dd4 * 4 + 1) * 512];
            float w2 = Wc[(dd4 * 4 + 2) * 512];
            float w3 = Wc[(dd4 * 4 + 3) * 512];
#pragma unroll
            for (int r = 0; r < 4; ++r) {
                float4 sv = *reinterpret_cast<const float4*>(id_s + (rg * 4 + r) * 128 + dd4 * 4);
                acc[r] += sv.x * w0 + sv.y * w1 + sv.z * w2 + sv.w * w3;
            }
        }
        float bj = kb1[j];
#pragma unroll
        for (int r = 0; r < 4; ++r)
            kh_s[(rg * 4 + r) * 512 + j] = gelu_exact(acc[r] + bj);
    }
    __syncthreads();
    for (int jb = 0; jb < 4; ++jb) {
        int j = jb * 64 + jj;
        float acc[4] = {0.f, 0.f, 0.f, 0.f};
        const float* Wc = kw2 + j;
        for (int h4 = 0; h4 < 128; ++h4) {
            float w0 = Wc[(h4 * 4 + 0) * 256];
            float w1 = Wc[(h4 * 4 + 1) * 256];
            float w2 = Wc[(h4 * 4 + 2) * 256];
            float w3 = Wc[(h4 * 4 + 3) * 256];
#pragma unroll
            for (int r = 0; r < 4; ++r) {
                float4 sv = *reinterpret_cast<const float4*>(kh_s + (rg * 4 + r) * 512 + h4 * 4);
                acc[r] += sv.x * w0 + sv.y * w1 + sv.z * w2 + sv.w * w3;
            }
        }
        float bj = kb2[j];
#pragma unroll
        for (int r = 0; r < 4; ++r)
            keys[(size_t)(n0 + rg * 4 + r) * 256 + j] = acc[r] + bj;
    }
}

// ---------------- per-step kernels ----------------

__global__ __launch_bounds__(256) void steer_kernel(
    const float* __restrict__ s_out, const float* __restrict__ node_id,
    const float* __restrict__ ws_out, const float* __restrict__ token_embed,
    const float* __restrict__ norm_w, const int* __restrict__ pos,
    float* __restrict__ steer, int t)
{
    int w = blockIdx.x;
    int b = w >> 4;
    int tid = threadIdx.x;
    int p = pos[w];
    float sc = s_out[((size_t)b * N_ + p) * DS_ + tid];
    float v = sc * sc;
    for (int off = 32; off > 0; off >>= 1) v += __shfl_down(v, off);
    __shared__ float red[4];
    if ((tid & 63) == 0) red[tid >> 6] = v;
    __syncthreads();
    float tot = red[0] + red[1] + red[2] + red[3];
    float r = rsqrtf(tot * (1.0f / DS_) + 1e-6f);
    float* st = steer + (size_t)w * DSTEER_;
    st[tid] = sc * r * norm_w[tid];
    if (tid < 128) st[256 + tid] = node_id[(size_t)p * DID_ + tid];
    st[384 + tid] = ws_out[(size_t)w * DS_ + tid];
    st[640 + tid] = token_embed[((size_t)b * T_ + t) * DS_ + tid];
}

__global__ __launch_bounds__(256) void layer1_kernel(
    const float* __restrict__ steer,
    const float* __restrict__ qw1, const float* __restrict__ qb1, float* __restrict__ q1,
    const float* __restrict__ W1, const float* __restrict__ b1, float* __restrict__ h1,
    const int* __restrict__ chunk_rows, const int* __restrict__ chunk_plane,
    const int* __restrict__ nchunks_p)
{
    __shared__ int rows_s[32];
    __shared__ float tile[32 * 128];
    int bid = blockIdx.x;
    if (bid < 64) {                       // q hidden: 8 rowtiles x 8 jtiles
        int rt = bid >> 3, jt = bid & 7;
        if (threadIdx.x < 32) rows_s[threadIdx.x] = rt * 32 + threadIdx.x;
        __syncthreads();
        mlp_tile(rows_s, steer, DSTEER_, qw1, QH_, jt * 64, false, qb1, true, q1, tile);
    } else {                              // content hidden: 16 chunks x 16 jtiles
        int b2 = bid - 64;
        int c = b2 >> 4, jt = b2 & 15;
        if (c >= *nchunks_p) return;
        if (threadIdx.x < 32) rows_s[threadIdx.x] = chunk_rows[c * 32 + threadIdx.x];
        int p = chunk_plane[c];
        __syncthreads();
        mlp_tile(rows_s, steer, DSTEER_, W1 + (size_t)p * DHID_ * DSTEER_, DHID_,
                 jt * 64, true, b1 + p * DHID_, true, h1, tile);
    }
}

__global__ __launch_bounds__(256) void layer2_kernel(
    const float* __restrict__ q1,
    const float* __restrict__ qw2, const float* __restrict__ qb2, float* __restrict__ qv,
    const float* __restrict__ h1, const float* __restrict__ W2,
    const float* __restrict__ b2, float* __restrict__ content,
    const int* __restrict__ chunk_rows, const int* __restrict__ chunk_plane,
    const int* __restrict__ nchunks_p)
{
    __shared__ int rows_s[32];
    __shared__ float tile[32 * 128];
    int bid = blockIdx.x;
    if (bid < 32) {                       // q out: 8 rowtiles x 4 jtiles
        int rt = bid >> 2, jt = bid & 3;
        if (threadIdx.x < 32) rows_s[threadIdx.x] = rt * 32 + threadIdx.x;
        __syncthreads();
        mlp_tile(rows_s, q1, QH_, qw2, QO_, jt * 64, false, qb2, false, qv, tile);
    } else {                              // content out: 16 chunks x 4 jtiles
        int b2i = bid - 32;
        int c = b2i >> 2, jt = b2i & 3;
        if (c >= *nchunks_p) return;
        if (threadIdx.x < 32) rows_s[threadIdx.x] = chunk_rows[c * 32 + threadIdx.x];
        int p = chunk_plane[c];
        __syncthreads();
        mlp_tile(rows_s, h1, DHID_, W2 + (size_t)p * DS_ * DHID_, DS_,
                 jt * 64, true, b2 + p * DS_, false, content, tile);
    }
}

__global__ __launch_bounds__(256) void score_kernel(
    const float* __restrict__ keys, const float* __restrict__ qv,
    const float* __restrict__ content, const int* __restrict__ neighbors,
    int* __restrict__ pos, float* __restrict__ s_out, float* __restrict__ ws_out,
    float* __restrict__ motor_out, float* __restrict__ co_out,
    float* __restrict__ vc_out, float* __restrict__ mp_all, int t)
{
    int w = blockIdx.x;
    int b = w >> 4;
    int tid = threadIdx.x;
    int pold = pos[w];
    __shared__ int nbr_s[32];
    __shared__ float part_s[8][32];
    __shared__ float sc_s[32];
    if (tid < 32) nbr_s[tid] = neighbors[(size_t)pold * K_ + tid];
    __syncthreads();
    int k = tid & 31, part = tid >> 5;
    int nk = nbr_s[k];
    const float* kp = keys + (size_t)nk * 256 + part * 32;
    const float* qp = qv + (size_t)w * 256 + part * 32;
    float acc = 0.f;
#pragma unroll
    for (int i = 0; i < 32; i += 4) {
        float4 kv = *reinterpret_cast<const float4*>(kp + i);
        float4 qq = *reinterpret_cast<const float4*>(qp + i);
        acc += kv.x * qq.x + kv.y * qq.y + kv.z * qq.z + kv.w * qq.w;
    }
    part_s[part][k] = acc;
    __syncthreads();
    if (tid < 32) {
        float s = 0.f;
#pragma unroll
        for (int p8 = 0; p8 < 8; ++p8) s += part_s[p8][tid];
        sc_s[tid] = s * SCORE_SCALE;
    }
    __syncthreads();
    if (tid < 32) {
        float sv = sc_s[tid];
        float m = sv;
        for (int off = 1; off < 32; off <<= 1) m = fmaxf(m, __shfl_xor(m, off));
        float e = expf(sv - m);
        float ssum = e;
        for (int off = 1; off < 32; off <<= 1) ssum += __shfl_xor(ssum, off);
        float prob = e / ssum;
        atomicAdd(&mp_all[t * 32 + tid], prob);
        // argmax (first occurrence of max)
        float bs = sv; int bi = tid;
        for (int off = 1; off < 32; off <<= 1) {
            float os = __shfl_xor(bs, off);
            int   oi = __shfl_xor(bi, off);
            if (os > bs || (os == bs && oi < bi)) { bs = os; bi = oi; }
        }
        if (tid == 0) {
            int next = nbr_s[bi];
            pos[w] = next;
            atomicAdd(&co_out[(size_t)pold * N_ + next], 1.0f);
            atomicAdd(&vc_out[next], 1.0f);
        }
    }
    // state updates (all 256 threads)
    float c = content[(size_t)w * DS_ + tid];
    atomicAdd(&s_out[((size_t)b * N_ + pold) * DS_ + tid], c);
    float wn = ws_out[(size_t)w * DS_ + tid] + c;
    ws_out[(size_t)w * DS_ + tid] = wn;
    atomicAdd(&motor_out[((size_t)b * T_ + t) * DS_ + tid], wn * (1.0f / H_));
}

__global__ __launch_bounds__(256) void final_kernel(
    const int* __restrict__ pos, const float* __restrict__ mp_all,
    float* __restrict__ pos_out, float* __restrict__ lb_out)
{
    int tid = threadIdx.x;
    pos_out[tid] = (float)pos[tid];
    float v = mp_all[tid] * (1.0f / 256.f);
    v = v * v;
    for (int off = 32; off > 0; off >>= 1) v += __shfl_down(v, off);
    __shared__ float red[4];
    if ((tid & 63) == 0) red[tid >> 6] = v;
    __syncthreads();
    if (tid == 0) lb_out[0] = (float)K_ * (red[0] + red[1] + red[2] + red[3]);
}

// ---------------- launch ----------------

extern "C" void kernel_launch(void* const* d_in, const int* in_sizes, int n_in,
                              void* d_out, int out_size, void* d_ws, size_t ws_size,
                              hipStream_t stream)
{
    const float* s_in      = (const float*)d_in[0];
    const float* node_id   = (const float*)d_in[1];
    const float* wstate_in = (const float*)d_in[2];
    const float* token     = (const float*)d_in[3];
    const float* norm_w    = (const float*)d_in[4];
    const float* W1        = (const float*)d_in[5];
    const float* b1        = (const float*)d_in[6];
    const float* W2        = (const float*)d_in[7];
    const float* b2        = (const float*)d_in[8];
    const float* qw1       = (const float*)d_in[9];
    const float* qb1       = (const float*)d_in[10];
    const float* qw2       = (const float*)d_in[11];
    const float* qb2       = (const float*)d_in[12];
    const float* kw1       = (const float*)d_in[13];
    const float* kb1       = (const float*)d_in[14];
    const float* kw2       = (const float*)d_in[15];
    const float* kb2       = (const float*)d_in[16];
    const int* walker_pos  = (const int*)d_in[17];
    const int* plane_idx   = (const int*)d_in[18];
    const int* neighbors   = (const int*)d_in[19];

    float* out = (float*)d_out;
    float* out_motor = out;                               // B*T*DS   = 32768
    float* out_s     = out_motor + 32768;                 // B*N*DS   = 16777216
    float* out_pos   = out_s + (size_t)16777216;          // B*H      = 256
    float* out_ws    = out_pos + 256;                     // B*H*DS   = 65536
    float* out_co    = out_ws + 65536;                    // N*N      = 16777216
    float* out_vc    = out_co + (size_t)16777216;         // N        = 4096
    float* out_lb    = out_vc + 4096;                     // 1

    float* ws = (float*)d_ws;
    float* keys    = ws;                                  // 4096*256  = 1048576
    float* steer   = keys + 1048576;                      // 256*896   = 229376
    float* h1      = steer + 229376;                      // 256*1024  = 262144
    float* q1v     = h1 + 262144;                         // 256*512   = 131072
    float* qvv     = q1v + 131072;                        // 256*256   = 65536
    float* content = qvv + 65536;                         // 256*256   = 65536
    float* mp_all  = content + 65536;                     // 8*32      = 256
    int* pos         = (int*)(mp_all + 256);              // 256
    int* plane_order = pos + 256;                         // 8*256 = 2048
    int* chunk_plane = plane_order + 2048;                // 16
    int* chunk_rows  = chunk_plane + 16;                  // 16*32 = 512
    int* nchunks_p   = chunk_rows + 512;                  // 1

    hipMemsetAsync(out_motor, 0, 32768 * sizeof(float), stream);
    hipMemsetAsync(out_co, 0, (size_t)(16777216 + 4096 + 1) * sizeof(float), stream);
    hipMemcpyAsync(out_s, s_in, (size_t)16777216 * sizeof(float),
                   hipMemcpyDeviceToDevice, stream);
    hipMemcpyAsync(out_ws, wstate_in, (size_t)65536 * sizeof(float),
                   hipMemcpyDeviceToDevice, stream);

    init_kernel<<<1, 256, 0, stream>>>(walker_pos, plane_idx, pos, mp_all,
                                       plane_order, chunk_plane, chunk_rows, nchunks_p);
    keys_kernel<<<256, 256, 0, stream>>>(node_id, kw1, kb1, kw2, kb2, keys);

    for (int t = 0; t < T_; ++t) {
        steer_kernel<<<256, 256, 0, stream>>>(out_s, node_id, out_ws, token,
                                              norm_w, pos, steer, t);
        layer1_kernel<<<64 + 256, 256, 0, stream>>>(steer, qw1, qb1, q1v,
                                                    W1, b1, h1,
                                                    chunk_rows, chunk_plane, nchunks_p);
        layer2_kernel<<<32 + 64, 256, 0, stream>>>(q1v, qw2, qb2, qvv,
                                                   h1, W2, b2, content,
                                                   chunk_rows, chunk_plane, nchunks_p);
        score_kernel<<<256, 256, 0, stream>>>(keys, qvv, content, neighbors, pos,
                                              out_s, out_ws, out_motor, out_co,
                                              out_vc, mp_all, t);
    }
    final_kernel<<<1, 256, 0, stream>>>(pos, mp_all, out_pos, out_lb);
}